// Round 1
// baseline (3944.920 us; speedup 1.0000x reference)
//
#include <hip/hip_runtime.h>

#define TT 2048

typedef _Float16 f16;
typedef _Float16 f16x2 __attribute__((ext_vector_type(2)));
typedef unsigned int u32;

// LDS layout: weights as f16 pairs along k (low half = even k), gate-major
// inner so lane-consecutive reads are conflict-free.
struct Smem {
  u32 wih1[32*256];   // [kpair][gate]  layer1 input weights (k=64 -> 32 pairs)
  u32 whh1[32*256];   // [kpair][gate]  layer1 recurrent
  u32 wih2[32*128];   // [kpair][gate]  layer2 input (k=64)
  u32 whh2[16*128];   // [kpair][gate]  layer2 recurrent (k=32)
  float ga1[2*256];   // [row][gate] layer1 gate preacts
  float ga2[2*128];
  u32 xbuf[2*2*32];   // [buf][row][kpair] x_t as f16 pairs (double buffered)
  u32 h1p[2*32];      // [row][kpair] h1 as f16 pairs
  u32 h2p[2*16];      // [row][kpair] h2
};

static __device__ __forceinline__ float fdot2f(u32 a, u32 b, float c) {
#if __has_builtin(__builtin_amdgcn_fdot2)
  return __builtin_amdgcn_fdot2(__builtin_bit_cast(f16x2, a),
                                __builtin_bit_cast(f16x2, b), c, false);
#else
  f16x2 av = __builtin_bit_cast(f16x2, a);
  f16x2 bv = __builtin_bit_cast(f16x2, b);
  return c + (float)av[0]*(float)bv[0] + (float)av[1]*(float)bv[1];
#endif
}

static __device__ __forceinline__ u32 packh2(float a, float b) {
  f16x2 v; v[0] = (f16)a; v[1] = (f16)b;
  return __builtin_bit_cast(u32, v);
}

static __device__ __forceinline__ float sigm(float x) {
  return 1.f / (1.f + __expf(-x));
}
static __device__ __forceinline__ float tanh_(float x) {
  x = fminf(15.f, fmaxf(-15.f, x));
  const float e = __expf(2.f*x);
  return (e - 1.f) / (e + 1.f);
}

__launch_bounds__(256, 1)
__global__ void lstm2_kernel(const float* __restrict__ x1,
                             const float* __restrict__ x2,
                             const float* __restrict__ Wih1,
                             const float* __restrict__ Whh1,
                             const float* __restrict__ bih1,
                             const float* __restrict__ bhh1,
                             const float* __restrict__ Wih2,
                             const float* __restrict__ Whh2,
                             const float* __restrict__ bih2,
                             const float* __restrict__ bhh2,
                             float* __restrict__ out)
{
  extern __shared__ char smem_raw[];
  Smem* s = (Smem*)smem_raw;
  const int tid = threadIdx.x;
  const int bid = blockIdx.x;
  const int which = bid >> 7;              // 0 -> x1, 1 -> x2
  const int rowbase = (bid & 127) << 1;    // 2 rows per WG
  const float* __restrict__ xg = which ? x2 : x1;

  // ---- one-time: weights -> LDS (f16 k-pairs) ----
  for (int i = tid; i < 32*256; i += 256) {
    const int kp = i >> 8, g = i & 255;
    const float2 w = *(const float2*)&Wih1[g*64 + 2*kp];
    s->wih1[kp*256 + g] = packh2(w.x, w.y);
  }
  for (int i = tid; i < 32*256; i += 256) {
    const int kp = i >> 8, g = i & 255;
    const float2 w = *(const float2*)&Whh1[g*64 + 2*kp];
    s->whh1[kp*256 + g] = packh2(w.x, w.y);
  }
  for (int i = tid; i < 32*128; i += 256) {
    const int kp = i >> 7, g = i & 127;
    const float2 w = *(const float2*)&Wih2[g*64 + 2*kp];
    s->wih2[kp*128 + g] = packh2(w.x, w.y);
  }
  for (int i = tid; i < 16*128; i += 256) {
    const int kp = i >> 7, g = i & 127;
    const float2 w = *(const float2*)&Whh2[g*32 + 2*kp];
    s->whh2[kp*128 + g] = packh2(w.x, w.y);
  }
  if (tid < 64) s->h1p[tid] = 0u;
  if (tid < 32) s->h2p[tid] = 0u;

  const float b1r = bih1[tid] + bhh1[tid];      // phase A: gate = tid
  const int g2 = tid & 127, r2 = tid >> 7;      // phase C mapping
  const float b2r = bih2[g2] + bhh2[g2];

  const int pr = tid >> 6;        // phase B row (tid<128)
  const int pk = tid & 63;        // phase B unit / x feature
  const int xbase = ((rowbase + pr) * TT) * 64 + pk;
  if (tid < 128) {
    ((f16*)s->xbuf)[pr*64 + pk] = (f16)xg[xbase];   // t=0 -> buf 0
  }
  float c1 = 0.f, c2 = 0.f;
  const int u2 = tid & 31, rr2 = tid >> 5;      // phase D mapping (tid<64)

  __syncthreads();

  #pragma unroll 2
  for (int t = 0; t < TT; ++t) {
    const int cur = t & 1, nxt = cur ^ 1;

    // prefetch x_{t+1} (latency hidden under phase A; committed in phase B)
    float xn = 0.f;
    if (tid < 128 && t + 1 < TT) xn = xg[xbase + (t+1)*64];

    // ---- phase A: layer-1 gates; thread = gate, loops both rows ----
    float a0e = b1r, a0o = 0.f, a1e = b1r, a1o = 0.f;
    {
      const u32* __restrict__ wp = s->wih1;
      const u32* __restrict__ xp0 = &s->xbuf[cur*64];
      const u32* __restrict__ xp1 = xp0 + 32;
      #pragma unroll
      for (int q = 0; q < 8; ++q) {
        const uint4 xv0 = *(const uint4*)(xp0 + 4*q);
        const uint4 xv1 = *(const uint4*)(xp1 + 4*q);
        const u32 w0 = wp[(4*q+0)*256 + tid];
        const u32 w1 = wp[(4*q+1)*256 + tid];
        const u32 w2 = wp[(4*q+2)*256 + tid];
        const u32 w3 = wp[(4*q+3)*256 + tid];
        a0e = fdot2f(w0, xv0.x, a0e); a1e = fdot2f(w0, xv1.x, a1e);
        a0o = fdot2f(w1, xv0.y, a0o); a1o = fdot2f(w1, xv1.y, a1o);
        a0e = fdot2f(w2, xv0.z, a0e); a1e = fdot2f(w2, xv1.z, a1e);
        a0o = fdot2f(w3, xv0.w, a0o); a1o = fdot2f(w3, xv1.w, a1o);
      }
      const u32* __restrict__ wh = s->whh1;
      const u32* __restrict__ hp0 = s->h1p;
      const u32* __restrict__ hp1 = hp0 + 32;
      #pragma unroll
      for (int q = 0; q < 8; ++q) {
        const uint4 hv0 = *(const uint4*)(hp0 + 4*q);
        const uint4 hv1 = *(const uint4*)(hp1 + 4*q);
        const u32 w0 = wh[(4*q+0)*256 + tid];
        const u32 w1 = wh[(4*q+1)*256 + tid];
        const u32 w2 = wh[(4*q+2)*256 + tid];
        const u32 w3 = wh[(4*q+3)*256 + tid];
        a0e = fdot2f(w0, hv0.x, a0e); a1e = fdot2f(w0, hv1.x, a1e);
        a0o = fdot2f(w1, hv0.y, a0o); a1o = fdot2f(w1, hv1.y, a1o);
        a0e = fdot2f(w2, hv0.z, a0e); a1e = fdot2f(w2, hv1.z, a1e);
        a0o = fdot2f(w3, hv0.w, a0o); a1o = fdot2f(w3, hv1.w, a1o);
      }
    }
    s->ga1[tid] = a0e + a0o;
    s->ga1[256 + tid] = a1e + a1o;
    __syncthreads();

    // ---- phase B: layer-1 cell update (tid<128) + commit x prefetch ----
    if (tid < 128) {
      const float gi = s->ga1[pr*256 + pk];
      const float gf = s->ga1[pr*256 + pk + 64];
      const float gg = s->ga1[pr*256 + pk + 128];
      const float go = s->ga1[pr*256 + pk + 192];
      const float iv = sigm(gi), fv = sigm(gf), gv = tanh_(gg), ov = sigm(go);
      c1 = fv*c1 + iv*gv;
      const float h = ov * tanh_(c1);
      ((f16*)s->h1p)[pr*64 + pk] = (f16)h;
      ((f16*)s->xbuf)[nxt*128 + pr*64 + pk] = (f16)xn;
    }
    __syncthreads();

    // ---- phase C: layer-2 gates (gate g2, row r2) ----
    float b0e = b2r, b0o = 0.f;
    {
      const u32* __restrict__ wp = s->wih2;
      const u32* __restrict__ hp = &s->h1p[r2*32];
      #pragma unroll
      for (int q = 0; q < 8; ++q) {
        const uint4 hv = *(const uint4*)(hp + 4*q);
        const u32 w0 = wp[(4*q+0)*128 + g2];
        const u32 w1 = wp[(4*q+1)*128 + g2];
        const u32 w2 = wp[(4*q+2)*128 + g2];
        const u32 w3 = wp[(4*q+3)*128 + g2];
        b0e = fdot2f(w0, hv.x, b0e);
        b0o = fdot2f(w1, hv.y, b0o);
        b0e = fdot2f(w2, hv.z, b0e);
        b0o = fdot2f(w3, hv.w, b0o);
      }
      const u32* __restrict__ wq = s->whh2;
      const u32* __restrict__ qp = &s->h2p[r2*16];
      #pragma unroll
      for (int q = 0; q < 4; ++q) {
        const uint4 hv = *(const uint4*)(qp + 4*q);
        const u32 w0 = wq[(4*q+0)*128 + g2];
        const u32 w1 = wq[(4*q+1)*128 + g2];
        const u32 w2 = wq[(4*q+2)*128 + g2];
        const u32 w3 = wq[(4*q+3)*128 + g2];
        b0e = fdot2f(w0, hv.x, b0e);
        b0o = fdot2f(w1, hv.y, b0o);
        b0e = fdot2f(w2, hv.z, b0e);
        b0o = fdot2f(w3, hv.w, b0o);
      }
    }
    s->ga2[r2*128 + g2] = b0e + b0o;
    __syncthreads();

    // ---- phase D: layer-2 cell update (tid<64) ----
    if (tid < 64) {
      const float gi = s->ga2[rr2*128 + u2];
      const float gf = s->ga2[rr2*128 + u2 + 32];
      const float gg = s->ga2[rr2*128 + u2 + 64];
      const float go = s->ga2[rr2*128 + u2 + 96];
      const float iv = sigm(gi), fv = sigm(gf), gv = tanh_(gg), ov = sigm(go);
      c2 = fv*c2 + iv*gv;
      const float h = ov * tanh_(c2);
      ((f16*)s->h2p)[rr2*32 + u2] = (f16)h;
      if (t == TT-1) out[which*8192 + (rowbase + rr2)*32 + u2] = h;
    }
    // No barrier here: h2p's consumer (phase C of t+1) is two barriers away;
    // ga2 is only rewritten after the next phase-B barrier.
  }
}

extern "C" void kernel_launch(void* const* d_in, const int* in_sizes, int n_in,
                              void* d_out, int out_size, void* d_ws, size_t ws_size,
                              hipStream_t stream) {
  const float* x1   = (const float*)d_in[0];
  const float* x2   = (const float*)d_in[1];
  const float* Wih1 = (const float*)d_in[2];
  const float* Whh1 = (const float*)d_in[3];
  const float* bih1 = (const float*)d_in[4];
  const float* bhh1 = (const float*)d_in[5];
  const float* Wih2 = (const float*)d_in[6];
  const float* Whh2 = (const float*)d_in[7];
  const float* bih2 = (const float*)d_in[8];
  const float* bhh2 = (const float*)d_in[9];
  float* out = (float*)d_out;

  static_assert(sizeof(Smem) <= 160*1024, "LDS overflow");
  // Dynamic LDS is ~92 KB (>64 KB default) — opt in. Host-side, not a
  // stream op, safe under graph capture; idempotent per call.
  (void)hipFuncSetAttribute((const void*)lstm2_kernel,
                            hipFuncAttributeMaxDynamicSharedMemorySize,
                            (int)sizeof(Smem));

  lstm2_kernel<<<dim3(256), dim3(256), sizeof(Smem), stream>>>(
      x1, x2, Wih1, Whh1, bih1, bhh1, Wih2, Whh2, bih2, bhh2, out);
}